// Round 1
// baseline (188.233 us; speedup 1.0000x reference)
//
#include <hip/hip_runtime.h>
#include <math.h>

#define BINS 100
#define DIM 512
#define D4 (DIM / 4)
#define LEAKY 0.1f

// Kernel 1: tabulate out(x) at G+1 grid points x_g = g/G, g = 0..G.
// One block (128 threads) per grid point. Full fp32 pipeline:
// h = leakyrelu(x*w1+b1); logits = h + w2@h + b2; w = softmax(logits);
// row = w @ emb  (512 floats -> table[g]).
__global__ __launch_bounds__(128) void build_table_kernel(
    const float* __restrict__ w1, const float* __restrict__ b1,
    const float* __restrict__ w2, const float* __restrict__ b2,
    const float* __restrict__ emb, float* __restrict__ table, int G)
{
    const int g = blockIdx.x;
    const int t = threadIdx.x;
    const float xv = (float)g / (float)G;

    __shared__ float h[BINS];
    __shared__ float wgt[BINS];
    __shared__ float red[128];

    if (t < BINS) {
        float hv = fmaf(xv, w1[t], b1[t]);
        h[t] = (hv >= 0.0f) ? hv : LEAKY * hv;
    }
    __syncthreads();

    float logit = -INFINITY;
    if (t < BINS) {
        float acc = b2[t];
        const float* wr = w2 + t * BINS;  // thread t streams row t of w2
        #pragma unroll 4
        for (int k = 0; k < BINS; ++k) acc = fmaf(h[k], wr[k], acc);
        logit = acc + h[t];  // BIN_ALPHA = 1.0 residual
    }

    // block max over logits
    red[t] = logit;
    __syncthreads();
    for (int s = 64; s > 0; s >>= 1) {
        if (t < s) red[t] = fmaxf(red[t], red[t + s]);
        __syncthreads();
    }
    const float m = red[0];
    __syncthreads();

    // exp + block sum
    const float e = (t < BINS) ? __expf(logit - m) : 0.0f;
    red[t] = e;
    __syncthreads();
    for (int s = 64; s > 0; s >>= 1) {
        if (t < s) red[t] += red[t + s];
        __syncthreads();
    }
    const float inv = 1.0f / red[0];
    if (t < BINS) wgt[t] = e * inv;
    __syncthreads();

    // row = wgt @ emb : thread t owns float4 slot t (dims 4t..4t+3), coalesced
    const float4* emb4 = (const float4*)emb;
    float4 acc = make_float4(0.f, 0.f, 0.f, 0.f);
    #pragma unroll 4
    for (int k = 0; k < BINS; ++k) {
        const float w = wgt[k];
        const float4 ev = emb4[k * D4 + t];
        acc.x = fmaf(w, ev.x, acc.x);
        acc.y = fmaf(w, ev.y, acc.y);
        acc.z = fmaf(w, ev.z, acc.z);
        acc.w = fmaf(w, ev.w, acc.w);
    }
    ((float4*)table)[g * D4 + t] = acc;
}

// Kernel 2: per-token linear interpolation of the table.
// One thread per float4 of output (token = i>>7, d4 = i&127).
__global__ __launch_bounds__(256) void interp_kernel(
    const float* __restrict__ x, const float4* __restrict__ table,
    float4* __restrict__ out, int G, int total4)
{
    const int i = blockIdx.x * 256 + threadIdx.x;
    if (i >= total4) return;
    const int token = i >> 7;   // D4 = 128 float4 per token
    const int d4 = i & (D4 - 1);

    float u = x[token] * (float)G;
    u = fmaxf(u, 0.0f);
    int g = (int)u;
    if (g > G - 1) g = G - 1;
    const float f = u - (float)g;

    const float4 a = table[g * D4 + d4];
    const float4 b = table[(g + 1) * D4 + d4];
    float4 r;
    r.x = fmaf(f, b.x - a.x, a.x);
    r.y = fmaf(f, b.y - a.y, a.y);
    r.z = fmaf(f, b.z - a.z, a.z);
    r.w = fmaf(f, b.w - a.w, a.w);
    out[i] = r;
}

extern "C" void kernel_launch(void* const* d_in, const int* in_sizes, int n_in,
                              void* d_out, int out_size, void* d_ws, size_t ws_size,
                              hipStream_t stream)
{
    const float* x   = (const float*)d_in[0];
    const float* w1  = (const float*)d_in[1];
    const float* b1  = (const float*)d_in[2];
    const float* w2  = (const float*)d_in[3];
    const float* b2  = (const float*)d_in[4];
    const float* emb = (const float*)d_in[5];

    const int N = in_sizes[0];  // B*S tokens (x has 1 scalar per token)

    // Table resolution: G=1024 -> 2.1 MB (fits per-XCD L2); shrink if ws is small.
    int G = 1024;
    while ((size_t)(G + 1) * DIM * sizeof(float) > ws_size && G > 32) G >>= 1;
    float* table = (float*)d_ws;

    hipLaunchKernelGGL(build_table_kernel, dim3(G + 1), dim3(128), 0, stream,
                       w1, b1, w2, b2, emb, table, G);

    const int total4 = N * D4;
    const int blocks = (total4 + 255) / 256;
    hipLaunchKernelGGL(interp_kernel, dim3(blocks), dim3(256), 0, stream,
                       x, (const float4*)table, (float4*)d_out, G, total4);
}

// Round 2
// 187.618 us; speedup vs baseline: 1.0033x; 1.0033x over previous
//
#include <hip/hip_runtime.h>
#include <math.h>

#define BINS 100
#define DIM 512
#define D4 (DIM / 4)
#define LEAKY 0.1f

typedef float f32x4 __attribute__((ext_vector_type(4)));

// Kernel 1: tabulate out(x) at G+1 grid points x_g = g/G.
// One block (128 threads) per grid point.
__global__ __launch_bounds__(128) void build_table_kernel(
    const float* __restrict__ w1, const float* __restrict__ b1,
    const float* __restrict__ w2, const float* __restrict__ b2,
    const float* __restrict__ emb, float* __restrict__ table, int G)
{
    const int g = blockIdx.x;
    const int t = threadIdx.x;
    const float xv = (float)g / (float)G;

    __shared__ float h[BINS];
    __shared__ float wgt[BINS];
    __shared__ float red[128];

    if (t < BINS) {
        float hv = fmaf(xv, w1[t], b1[t]);
        h[t] = (hv >= 0.0f) ? hv : LEAKY * hv;
    }
    __syncthreads();

    float logit = -INFINITY;
    if (t < BINS) {
        float acc = b2[t];
        const float* wr = w2 + t * BINS;
        #pragma unroll 4
        for (int k = 0; k < BINS; ++k) acc = fmaf(h[k], wr[k], acc);
        logit = acc + h[t];  // BIN_ALPHA = 1.0 residual
    }

    red[t] = logit;
    __syncthreads();
    for (int s = 64; s > 0; s >>= 1) {
        if (t < s) red[t] = fmaxf(red[t], red[t + s]);
        __syncthreads();
    }
    const float m = red[0];
    __syncthreads();

    const float e = (t < BINS) ? __expf(logit - m) : 0.0f;
    red[t] = e;
    __syncthreads();
    for (int s = 64; s > 0; s >>= 1) {
        if (t < s) red[t] += red[t + s];
        __syncthreads();
    }
    const float inv = 1.0f / red[0];
    if (t < BINS) wgt[t] = e * inv;
    __syncthreads();

    // row = wgt @ emb : thread t owns float4 slot t, coalesced over lanes
    const f32x4* emb4 = (const f32x4*)emb;
    f32x4 acc = (f32x4)(0.0f);
    #pragma unroll 4
    for (int k = 0; k < BINS; ++k) {
        acc += wgt[k] * emb4[k * D4 + t];
    }
    ((f32x4*)table)[g * D4 + t] = acc;
}

// Kernel 2: per-token linear interpolation of the table.
// One thread per float4 of output. Table reads are L2-resident (1 MB);
// output stores are nontemporal (pure streaming write).
__global__ __launch_bounds__(256) void interp_kernel(
    const float* __restrict__ x, const f32x4* __restrict__ table,
    f32x4* __restrict__ out, int G, int total4)
{
    const int i = blockIdx.x * 256 + threadIdx.x;
    if (i >= total4) return;
    const int token = i >> 7;   // D4 = 128 float4 per token
    const int d4 = i & (D4 - 1);

    float u = x[token] * (float)G;
    u = fmaxf(u, 0.0f);
    int g = (int)u;
    if (g > G - 1) g = G - 1;
    const float f = u - (float)g;

    const f32x4 a = table[g * D4 + d4];
    const f32x4 b = table[(g + 1) * D4 + d4];
    const f32x4 r = a + f * (b - a);
    __builtin_nontemporal_store(r, &out[i]);
}

extern "C" void kernel_launch(void* const* d_in, const int* in_sizes, int n_in,
                              void* d_out, int out_size, void* d_ws, size_t ws_size,
                              hipStream_t stream)
{
    const float* x   = (const float*)d_in[0];
    const float* w1  = (const float*)d_in[1];
    const float* b1  = (const float*)d_in[2];
    const float* w2  = (const float*)d_in[3];
    const float* b2  = (const float*)d_in[4];
    const float* emb = (const float*)d_in[5];

    const int N = in_sizes[0];  // B*S tokens

    int G = 512;                // table = (G+1)*512*4B ~= 1.05 MB, per-XCD L2 resident
    while ((size_t)(G + 1) * DIM * sizeof(float) > ws_size && G > 32) G >>= 1;
    float* table = (float*)d_ws;

    hipLaunchKernelGGL(build_table_kernel, dim3(G + 1), dim3(128), 0, stream,
                       w1, b1, w2, b2, emb, table, G);

    const int total4 = N * D4;
    const int blocks = (total4 + 255) / 256;
    hipLaunchKernelGGL(interp_kernel, dim3(blocks), dim3(256), 0, stream,
                       x, (const f32x4*)table, (f32x4*)d_out, G, total4);
}

// Round 3
// 173.432 us; speedup vs baseline: 1.0853x; 1.0818x over previous
//
#include <hip/hip_runtime.h>
#include <math.h>

#define BINS 100
#define DIM 512
#define D4 (DIM / 4)
#define LEAKY 0.1f

typedef float f32x4 __attribute__((ext_vector_type(4)));

// Kernel 1: tabulate out(x) at G+1 grid points x_g = g/G.
// One block (128 threads) per grid point.
__global__ __launch_bounds__(128) void build_table_kernel(
    const float* __restrict__ w1, const float* __restrict__ b1,
    const float* __restrict__ w2, const float* __restrict__ b2,
    const float* __restrict__ emb, float* __restrict__ table, int G)
{
    const int g = blockIdx.x;
    const int t = threadIdx.x;
    const float xv = (float)g / (float)G;

    __shared__ float h[BINS];
    __shared__ float wgt[BINS];
    __shared__ float red[128];

    if (t < BINS) {
        float hv = fmaf(xv, w1[t], b1[t]);
        h[t] = (hv >= 0.0f) ? hv : LEAKY * hv;
    }
    __syncthreads();

    float logit = -INFINITY;
    if (t < BINS) {
        float acc = b2[t];
        const float* wr = w2 + t * BINS;
        #pragma unroll 4
        for (int k = 0; k < BINS; ++k) acc = fmaf(h[k], wr[k], acc);
        logit = acc + h[t];  // BIN_ALPHA = 1.0 residual
    }

    red[t] = logit;
    __syncthreads();
    for (int s = 64; s > 0; s >>= 1) {
        if (t < s) red[t] = fmaxf(red[t], red[t + s]);
        __syncthreads();
    }
    const float m = red[0];
    __syncthreads();

    const float e = (t < BINS) ? __expf(logit - m) : 0.0f;
    red[t] = e;
    __syncthreads();
    for (int s = 64; s > 0; s >>= 1) {
        if (t < s) red[t] += red[t + s];
        __syncthreads();
    }
    const float inv = 1.0f / red[0];
    if (t < BINS) wgt[t] = e * inv;
    __syncthreads();

    // row = wgt @ emb : thread t owns float4 slot t, coalesced over lanes
    const f32x4* emb4 = (const f32x4*)emb;
    f32x4 acc = (f32x4)(0.0f);
    #pragma unroll 4
    for (int k = 0; k < BINS; ++k) {
        acc += wgt[k] * emb4[k * D4 + t];
    }
    ((f32x4*)table)[g * D4 + t] = acc;
}

// Kernel 2: per-token linear interpolation of the table.
// 8 tokens per 256-thread block; each 32-lane group owns one token and
// covers its 128 float4s in 4 coalesced 512B runs. Table reads hit L2
// (table = 526 KB); output stores are nontemporal streaming writes.
__global__ __launch_bounds__(256) void interp_kernel(
    const float* __restrict__ x, const f32x4* __restrict__ table,
    f32x4* __restrict__ out, int G, int nTokens)
{
    const int t = threadIdx.x;
    const int lane32 = t & 31;
    const int token = blockIdx.x * 8 + (t >> 5);
    if (token >= nTokens) return;

    float u = x[token] * (float)G;
    u = fmaxf(u, 0.0f);
    int g = (int)u;
    if (g > G - 1) g = G - 1;
    const float f = u - (float)g;

    const f32x4* __restrict__ rowA = table + g * D4;
    const f32x4* __restrict__ rowB = rowA + D4;
    f32x4* o = out + (size_t)token * D4;

    #pragma unroll
    for (int j = 0; j < 4; ++j) {
        const int d4 = lane32 + 32 * j;
        const f32x4 a = rowA[d4];
        const f32x4 b = rowB[d4];
        __builtin_nontemporal_store(a + f * (b - a), &o[d4]);
    }
}

extern "C" void kernel_launch(void* const* d_in, const int* in_sizes, int n_in,
                              void* d_out, int out_size, void* d_ws, size_t ws_size,
                              hipStream_t stream)
{
    const float* x   = (const float*)d_in[0];
    const float* w1  = (const float*)d_in[1];
    const float* b1  = (const float*)d_in[2];
    const float* w2  = (const float*)d_in[3];
    const float* b2  = (const float*)d_in[4];
    const float* emb = (const float*)d_in[5];

    const int N = in_sizes[0];  // B*S tokens

    int G = 256;                // table = (G+1)*512*4B ~= 526 KB, per-XCD L2 resident
    while ((size_t)(G + 1) * DIM * sizeof(float) > ws_size && G > 32) G >>= 1;
    float* table = (float*)d_ws;

    hipLaunchKernelGGL(build_table_kernel, dim3(G + 1), dim3(128), 0, stream,
                       w1, b1, w2, b2, emb, table, G);

    const int blocks = (N + 7) / 8;  // 8 tokens per block
    hipLaunchKernelGGL(interp_kernel, dim3(blocks), dim3(256), 0, stream,
                       x, (const f32x4*)table, (f32x4*)d_out, G, N);
}